// Round 1
// 60.507 us; speedup vs baseline: 1.0263x; 1.0263x over previous
//
#include <hip/hip_runtime.h>

__device__ __forceinline__ float relu_f(float v) { return fmaxf(v, 0.0f); }

// Exact replica of the reference _hat() in fp32 (precise division kept:
// absmax is currently 0.0 and must stay bit-exact).
__device__ __forceinline__ float hatf(float xf, float xm, float xc, float xp) {
    float left  = relu_f(1.0f - relu_f(xc - xf) / (xc - xm));
    float right = relu_f(1.0f - relu_f(xf - xc) / (xp - xc));
    return left + right - 1.0f;
}

__global__ __launch_bounds__(256) void MeshNN_23330262352119_kernel(
        const float* __restrict__ x,
        const float* __restrict__ coords,
        const float* __restrict__ w_uu,
        const float* __restrict__ w_dd,
        float* __restrict__ out,
        int n, int np) {
    extern __shared__ float smem[];
    float* sc = smem;          // np node coords
    float* sw = smem + np;     // np-2 interior weights (offset 2048 B, 16B aligned)

    const int tid  = threadIdx.x;
    const int i2   = blockIdx.x * blockDim.x + tid;
    const int base = i2 << 1;

    // Issue the per-thread x load FIRST: its HBM/L2 latency overlaps the
    // LDS staging + barrier below (G7 ILP). Previously it was issued after
    // __syncthreads(), fully exposing the latency at 2 waves/SIMD.
    float2 xv = make_float2(0.0f, 0.0f);
    const bool full = (base + 1 < n);
    if (full) xv = ((const float2*)x)[i2];
    float x_tail = 0.0f;
    const bool tail = (!full) && (base < n);
    if (tail) x_tail = x[base];

    // Wave-uniform values via global s_load, independent of the barrier
    // (previously read through LDS, chaining setup behind staging).
    const float c0  = coords[0];
    const float cL  = coords[np - 1];
    const float wd0 = w_dd[0];
    const float wd1 = w_dd[1];

    // Vectorized staging: 512 coords = 128 float4 (single iteration),
    // 510 weights = 127 float4 + 2-float scalar tail.
    const int nc4 = np >> 2;
    for (int i = tid; i < nc4; i += blockDim.x)
        ((float4*)sc)[i] = ((const float4*)coords)[i];
    const int nw  = np - 2;
    const int nw4 = nw >> 2;
    for (int i = tid; i < nw4; i += blockDim.x)
        ((float4*)sw)[i] = ((const float4*)w_uu)[i];
    for (int i = (nw4 << 2) + tid; i < nw; i += blockDim.x)
        sw[i] = w_uu[i];
    __syncthreads();

    const float L     = cL - c0;
    const float ghost = L / 1000.0f;
    const float inv_h = (float)(np - 1) / L;
    const int   jmax  = np - 2;    // last interval index [sc[jmax], sc[jmax+1]]

    if (tail) {
        // tail guard (not taken at n=262144, but safe; all threads already
        // passed the barrier)
        float xf = x_tail;
        int j = (int)floorf((xf - c0) * inv_h);
        j = min(max(j, 0), jmax);
        if (j < jmax && xf > sc[j + 1]) ++j;
        else if (j > 0 && xf < sc[j])   --j;
        float u = 0.0f;
        if (j >= 1)        u += sw[j - 1] * hatf(xf, sc[j - 1], sc[j], sc[j + 1]);
        if (j <= jmax - 1) u += sw[j]     * hatf(xf, sc[j], sc[j + 1], sc[j + 2]);
        if (j == 0)        u += wd0 * hatf(xf, c0 - ghost, c0, sc[1]);
        if (j == jmax)     u += wd1 * hatf(xf, sc[np - 2], cL, cL + ghost);
        out[base] = u;
        return;
    }
    if (!full) return;

    float xs[2] = {xv.x, xv.y};
    float r[2];

    #pragma unroll
    for (int k = 0; k < 2; ++k) {
        float xf = xs[k];
        // locate containing interval j: sc[j] <= xf <= sc[j+1]
        int j = (int)floorf((xf - c0) * inv_h);
        j = min(max(j, 0), jmax);
        if (j < jmax && xf > sc[j + 1]) ++j;
        else if (j > 0 && xf < sc[j])   --j;

        float u = 0.0f;
        // interior hat centered at node j (basis index j-1), support [sc[j-1], sc[j+1]]
        if (j >= 1)
            u += sw[j - 1] * hatf(xf, sc[j - 1], sc[j], sc[j + 1]);
        // interior hat centered at node j+1 (basis index j), support [sc[j], sc[j+2]]
        if (j <= jmax - 1)
            u += sw[j] * hatf(xf, sc[j], sc[j + 1], sc[j + 2]);
        // boundary hats
        if (j == 0)
            u += wd0 * hatf(xf, c0 - ghost, c0, sc[1]);
        if (j == jmax)
            u += wd1 * hatf(xf, sc[np - 2], cL, cL + ghost);
        r[k] = u;
    }

    ((float2*)out)[i2] = make_float2(r[0], r[1]);
}

extern "C" void kernel_launch(void* const* d_in, const int* in_sizes, int n_in,
                              void* d_out, int out_size, void* d_ws, size_t ws_size,
                              hipStream_t stream) {
    const float* x      = (const float*)d_in[0];
    const float* coords = (const float*)d_in[1];
    const float* w_uu   = (const float*)d_in[2];
    const float* w_dd   = (const float*)d_in[3];
    float* out = (float*)d_out;

    const int n  = in_sizes[0];   // 262144
    const int np = in_sizes[1];   // 512

    const int n2    = (n + 1) >> 1;
    const int block = 256;
    const int grid  = (n2 + block - 1) / block;   // 512 blocks -> 2 blocks/CU, 8 waves/CU
    const size_t smem = (size_t)(np + (np - 2)) * sizeof(float);

    MeshNN_23330262352119_kernel<<<grid, block, smem, stream>>>(
        x, coords, w_uu, w_dd, out, n, np);
}